// Round 13
// baseline (540.533 us; speedup 1.0000x reference)
//
#include <hip/hip_runtime.h>
#include <hip/hip_bf16.h>
#include <cstdint>
#include <cstddef>

// Problem constants (fixed shapes per reference)
#define NROWS 8192
#define DIM   1024        // elements = bytes in fp8
#define BMR 128           // block rows (2 waves x 64)
#define BNC 128           // block cols
#define BKB 128           // K bytes per iteration; 8 iterations
#define NBLK 2080         // 64*65/2 triangle tiles = 8 XCDs x 260
#define EPS 1e-8f
// E pre-scaled by sqrt(10*log2(e)) so MFMA accumulates 10*log2(e)*<a,b>;
// epilogue is a bare exp2f. fp8 e4m3 numerics validated end-to-end by R10
// (passed correctness with this conversion + this MFMA's layouts).
#define PRESCALE 3.798288f

typedef int    intx8   __attribute__((ext_vector_type(8)));
typedef float  floatx4 __attribute__((ext_vector_type(4)));

typedef __attribute__((address_space(1))) const void CGV;
typedef __attribute__((address_space(3))) void LV;

__device__ __forceinline__ void async_load16(const void* g, void* l) {
    __builtin_amdgcn_global_load_lds((CGV*)g, (LV*)l, 16, 0, 0);
}

// two swizzled 16B LDS chunks -> one 32B K-contiguous fp8 MFMA operand
__device__ __forceinline__ intx8 ldfrag(const unsigned char* base, int o0, int o1) {
    int4 lo = *(const int4*)(base + o0);
    int4 hi = *(const int4*)(base + o1);
    intx8 r;
    r[0] = lo.x; r[1] = lo.y; r[2] = lo.z; r[3] = lo.w;
    r[4] = hi.x; r[5] = hi.y; r[6] = hi.z; r[7] = hi.w;
    return r;
}

// ---------------------------------------------------------------------------
// Kernel A: fp32 -> fp8 e4m3 (hardware cvt_pk, PRESCALE folded; R10-validated).
// First 64 blocks also zero the 16384-float accumulator region.
// ---------------------------------------------------------------------------
__global__ __launch_bounds__(256) void convert_kernel(
    const float* __restrict__ in, unsigned int* __restrict__ out,
    float* __restrict__ accum /* all_sum ++ pos_sum, 2*NROWS floats */)
{
    int i = (blockIdx.x * 256 + threadIdx.x) * 4;
    float4 v = *(const float4*)(in + i);
    int p = __builtin_amdgcn_cvt_pk_fp8_f32(v.x * PRESCALE, v.y * PRESCALE, 0, false);
    p     = __builtin_amdgcn_cvt_pk_fp8_f32(v.z * PRESCALE, v.w * PRESCALE, p, true);
    out[i >> 2] = (unsigned int)p;
    if (blockIdx.x < (2 * NROWS) / 256)
        accum[blockIdx.x * 256 + threadIdx.x] = 0.0f;
}

// ---------------------------------------------------------------------------
// Kernel B: symmetric-half fused GEMM — R12's fat-tile 2-wave structure with
// R10's fp8 MX-scaled datapath (correctness validated by R10's pass).
// R10's perf failure was __launch_bounds__(256,3) forcing <=170 regs ->
// scratch spills (WRITE_SIZE 728 MB). Here: bounds(128,2) (256-reg budget),
// bF loaded per-nt (1 live B frag) -> no spills.
// Per wave-iter: 24 ds_read_b128 feed 32 mfma_scale_16x16x128 (2x bf16 rate);
// 8 K-iterations (vs 16) halve barrier drains; all pipe demands ~halve vs R12.
// LDS rows are 128 B (8 chunks): bank group = slot%8 (row stride == 0 mod 8),
// storage slot s of row r holds global chunk s ^ (r&7); quad q reads slots
// (2q)^(colw&7), (2q+1)^(colw&7) -> all 8 groups 2-way (free). Staging writes
// cycle groups 0-7 (free).
// UNIFORM symmetry (R11/R12-verified): keep strictly-lower (grow > gcol);
// each element feeds row grow AND col gcol. XCD-local tile order (R9).
// ---------------------------------------------------------------------------
__global__ __launch_bounds__(128, 2) void gemm_fused_kernel(
    const unsigned char* __restrict__ E,   // fp8 e4m3 (prescaled), [NROWS][DIM]
    const int*           __restrict__ labels,
    float*               __restrict__ all_sum,
    float*               __restrict__ pos_sum)
{
    __shared__ __align__(16) unsigned char sA[BMR * BKB];   // 16 KB
    __shared__ __align__(16) unsigned char sB[BNC * BKB];   // 16 KB

    const int tid  = threadIdx.x;
    const int lane = tid & 63;
    const int w    = tid >> 6;      // wave 0/1 -> rows w*64..w*64+63 of block
    const int colw = lane & 15;
    const int quad = lane >> 4;

    // XCD-local linear tile id, then sqrt triangle decode (strips of 128).
    const int b = blockIdx.x;
    const int t = (b & 7) * 260 + (b >> 3);     // 2080 = 8 x 260
    int bi = (int)((sqrtf(8.0f * (float)t + 1.0f) - 1.0f) * 0.5f);
    while ((bi + 1) * (bi + 2) / 2 <= t) ++bi;
    while (bi * (bi + 1) / 2 > t) --bi;
    const int bj = t - bi * (bi + 1) / 2;

    const int rBase = bi * BMR;     // rows (A tile)
    const int cBase = bj * BNC;     // cols (B tile)

    // Staging: tile = 128 rows x 8 chunks of 16B = 1024 chunks; 128 threads x
    // 8 passes (rows srow + 16j). Slot (t&7) of row srow holds global chunk
    // (t&7) ^ (srow&7); srow&7 invariant under +16.
    const int srow = tid >> 3;                          // 0..15
    const int scol = (((tid & 7) ^ (srow & 7)) << 4);   // byte col 0..112
    const int e0   = tid * 16;                          // LDS byte offset/pass

    floatx4 acc[4][8];
    #pragma unroll
    for (int i = 0; i < 4; ++i)
        #pragma unroll
        for (int j = 0; j < 8; ++j)
            acc[i][j] = (floatx4)0.0f;

    // Fragment reads: A row = w*64 + mt*16 + colw; B row = nt*16 + colw.
    // Lane's K-bytes = quad*32..quad*32+31 = chunks 2q,2q+1, stored at slots
    // ^(row&7) = ^(colw&7).
    const int swz = colw & 7;
    const int c0  = (((quad << 1)    ) ^ swz) << 4;
    const int c1  = (((quad << 1) | 1) ^ swz) << 4;
    const int aRow0 = (w * 64 + colw) * BKB;
    const int bRow0 = colw * BKB;

    const size_t gA0 = (size_t)(rBase + srow) * DIM + scol;
    const size_t gB0 = (size_t)(cBase + srow) * DIM + scol;
    const size_t rstep = (size_t)16 * DIM;

    for (int k0 = 0; k0 < DIM; k0 += BKB) {
        __syncthreads();   // previous compute done before overwrite
        #pragma unroll
        for (int j = 0; j < 8; ++j)
            async_load16(E + gA0 + j * rstep + k0, &sA[e0 + j * 2048]);
        #pragma unroll
        for (int j = 0; j < 8; ++j)
            async_load16(E + gB0 + j * rstep + k0, &sB[e0 + j * 2048]);
        __syncthreads();   // vmcnt drained by compiler before barrier

        intx8 aF[4];
        #pragma unroll
        for (int mt = 0; mt < 4; ++mt)
            aF[mt] = ldfrag(&sA[aRow0 + mt * 16 * BKB], c0, c1);

        #pragma unroll
        for (int nt = 0; nt < 8; ++nt) {
            intx8 bF = ldfrag(&sB[bRow0 + nt * 16 * BKB], c0, c1);
            #pragma unroll
            for (int mt = 0; mt < 4; ++mt)
                acc[mt][nt] = __builtin_amdgcn_mfma_scale_f32_16x16x128_f8f6f4(
                    aF[mt], bF, acc[mt][nt],
                    0, 0,          // cbsz=0 (A fp8 e4m3), blgp=0 (B fp8 e4m3)
                    0, 127,        // opsel_a, scale_a = E8M0 127 -> 1.0
                    0, 127);       // opsel_b, scale_b
        }
    }

    // Epilogue. C/D layout (16x16, shape-determined): col=lane&15, row=quad*4+reg.
    // Uniform rule (R11/R12-verified): element (grow, gcol) counts iff
    // grow > gcol; contributes to row grow AND col gcol.
    float labc[8];
    int   gcol[8];
    #pragma unroll
    for (int nt = 0; nt < 8; ++nt) {
        gcol[nt] = cBase + nt * 16 + colw;
        labc[nt] = (float)labels[gcol[nt]];
    }

    float colAll[8] = {0.f, 0.f, 0.f, 0.f, 0.f, 0.f, 0.f, 0.f};
    float colPos[8] = {0.f, 0.f, 0.f, 0.f, 0.f, 0.f, 0.f, 0.f};

    #pragma unroll
    for (int mt = 0; mt < 4; ++mt) {
        const int growBase = rBase + w * 64 + mt * 16 + quad * 4;
        #pragma unroll
        for (int r = 0; r < 4; ++r) {
            const int grow = growBase + r;
            const float labr = (float)labels[grow];
            float sAll = 0.f, sPos = 0.f;
            #pragma unroll
            for (int nt = 0; nt < 8; ++nt) {
                float ev = exp2f(acc[mt][nt][r]);   // PRESCALE folded into E
                ev = (grow > gcol[nt]) ? ev : 0.0f; // strictly-lower only
                sAll += ev;
                sPos += ev * labc[nt];
                colAll[nt] += ev;
                colPos[nt] += ev * labr;
            }
            // row-reduce across the 16 lanes (same quad) sharing this row
            #pragma unroll
            for (int off = 1; off < 16; off <<= 1) {
                sAll += __shfl_xor(sAll, off);
                sPos += __shfl_xor(sPos, off);
            }
            if (colw == 0 && sAll != 0.f) {
                atomicAdd(&all_sum[grow], sAll);
                atomicAdd(&pos_sum[grow], sPos);
            }
        }
    }

    // col-reduce: sum across quads (lanes differing in bits 4,5)
    #pragma unroll
    for (int nt = 0; nt < 8; ++nt) {
        float a = colAll[nt], p = colPos[nt];
        a += __shfl_xor(a, 16);  p += __shfl_xor(p, 16);
        a += __shfl_xor(a, 32);  p += __shfl_xor(p, 32);
        if (quad == 0 && a != 0.f) {
            atomicAdd(&all_sum[gcol[nt]], a);
            atomicAdd(&pos_sum[gcol[nt]], p);
        }
    }
}

// ---------------------------------------------------------------------------
// Kernel C: loss = mean over rows with lab==1 of -log(pos/(all+eps)); 0 if n_ref<2
// ---------------------------------------------------------------------------
__global__ __launch_bounds__(1024) void finalize_kernel(
    const float* __restrict__ all_sum,
    const float* __restrict__ pos_sum,
    const int*   __restrict__ labels,
    float*       __restrict__ out)
{
    __shared__ float sSum[1024];
    __shared__ float sCnt[1024];
    const int tid = threadIdx.x;
    float lsum = 0.f, lcnt = 0.f;
    for (int i = tid; i < NROWS; i += 1024) {
        if (labels[i] > 0) {
            float p = pos_sum[i];
            float a = all_sum[i] + EPS;
            lsum += -logf(p / a);
            lcnt += 1.0f;
        }
    }
    sSum[tid] = lsum;
    sCnt[tid] = lcnt;
    __syncthreads();
    for (int s = 512; s > 0; s >>= 1) {
        if (tid < s) { sSum[tid] += sSum[tid + s]; sCnt[tid] += sCnt[tid + s]; }
        __syncthreads();
    }
    if (tid == 0) {
        float n = sCnt[0];
        out[0] = (n < 2.0f) ? 0.0f : sSum[0] / fmaxf(n, 1.0f);
    }
}

// ---------------------------------------------------------------------------
extern "C" void kernel_launch(void* const* d_in, const int* in_sizes, int n_in,
                              void* d_out, int out_size, void* d_ws, size_t ws_size,
                              hipStream_t stream) {
    const float* emb    = (const float*)d_in[0];
    const int*   labels = (const int*)d_in[1];
    float*       out    = (float*)d_out;

    // workspace layout: [fp8 E: 8 MB][all_sum: 32 KB][pos_sum: 32 KB]
    unsigned char* Efp8 = (unsigned char*)d_ws;
    const size_t embBytes = (size_t)NROWS * DIM;   // 1 B/elem
    float* all_sum = (float*)((char*)d_ws + embBytes);
    float* pos_sum = all_sum + NROWS;

    convert_kernel<<<(NROWS * DIM) / (4 * 256), 256, 0, stream>>>(
        emb, (unsigned int*)Efp8, all_sum);

    gemm_fused_kernel<<<NBLK, 128, 0, stream>>>(Efp8, labels, all_sum, pos_sum);

    finalize_kernel<<<1, 1024, 0, stream>>>(all_sum, pos_sum, labels, out);
}

// Round 14
// 199.325 us; speedup vs baseline: 2.7118x; 2.7118x over previous
//
#include <hip/hip_runtime.h>
#include <hip/hip_bf16.h>
#include <cstdint>
#include <cstddef>

// Problem constants (fixed shapes per reference)
#define NROWS 8192
#define DIM   1024
#define BMR 128           // block rows (2 waves x 64)
#define BNC 128           // block cols
#define BK  64            // K depth per iteration; 16 iterations
#define NITER (DIM / BK)
#define NBLK 2080         // 64*65/2 triangle tiles = 8 XCDs x 260
#define EPS 1e-8f
// E pre-scaled by sqrt(10*log2(e)) so MFMA accumulates 10*log2(e)*<a,b>;
// epilogue is a bare exp2f.
#define PRESCALE 3.798288f

typedef short  bf16x8  __attribute__((ext_vector_type(8)));
typedef float  floatx4 __attribute__((ext_vector_type(4)));

typedef __attribute__((address_space(1))) const void CGV;
typedef __attribute__((address_space(3))) void LV;

__device__ __forceinline__ void async_load16(const void* g, void* l) {
    __builtin_amdgcn_global_load_lds((CGV*)g, (LV*)l, 16, 0, 0);
}

__device__ __forceinline__ unsigned short f2bf_rne(float f) {
    union { float f; unsigned u; } c; c.f = f;
    unsigned u = c.u;
    unsigned r = (u + 0x7fffu + ((u >> 16) & 1u)) >> 16;
    return (unsigned short)r;
}

// ---------------------------------------------------------------------------
// Kernel A: fp32 -> bf16 (RNE) with PRESCALE folded in. First 64 blocks also
// zero the 16384-float accumulator region.
// ---------------------------------------------------------------------------
__global__ __launch_bounds__(256) void convert_kernel(
    const float* __restrict__ in, unsigned short* __restrict__ out,
    float* __restrict__ accum /* all_sum ++ pos_sum, 2*NROWS floats */)
{
    int i = (blockIdx.x * 256 + threadIdx.x) * 4;
    float4 v = *(const float4*)(in + i);
    ushort4 o;
    o.x = f2bf_rne(v.x * PRESCALE);
    o.y = f2bf_rne(v.y * PRESCALE);
    o.z = f2bf_rne(v.z * PRESCALE);
    o.w = f2bf_rne(v.w * PRESCALE);
    *(ushort4*)(out + i) = o;
    if (blockIdx.x < (2 * NROWS) / 256)
        accum[blockIdx.x * 256 + threadIdx.x] = 0.0f;
}

// ---------------------------------------------------------------------------
// Kernel B: symmetric-half fused GEMM — R12 structure with A served
// DIRECT-FROM-GLOBAL (register double-buffer), B via LDS.
// Evidence (R12 counters + m134): LDS read pipe was 100% busy (8 waves x 24
// ds_read_b128 x 12cyc = 2304 cyc/K-iter/CU = measured wall). A-fragments are
// K-contiguous rows of E (m=lane&15 needs bytes [row*DIM + k0+h*32+quad*8)),
// so A skips LDS entirely: ds_reads/wave-iter 24->16, staged loads 16->8.
// A loads for iter i+1 issue right AFTER sync2(i) -> a full compute phase of
// slack before the drain at sync2(i+1) (R7-proven pattern). K-loop fully
// unrolled: A double-buffer indices are compile-time (no dynamic-index
// scratch, R5 lesson).
// B LDS layout/swizzle verbatim R12 (0 conflicts measured).
// UNIFORM symmetry (R11/R12-verified): keep strictly-lower (grow > gcol).
// XCD-local tile order (R9).
// ---------------------------------------------------------------------------
__global__ __launch_bounds__(128, 2) void gemm_fused_kernel(
    const unsigned short* __restrict__ E,   // bf16 bits (prescaled), [NROWS][DIM]
    const int*            __restrict__ labels,
    float*                __restrict__ all_sum,
    float*                __restrict__ pos_sum)
{
    __shared__ __align__(16) unsigned short sB[BNC * BK];   // 16 KB (B only)

    const int tid  = threadIdx.x;
    const int lane = tid & 63;
    const int w    = tid >> 6;      // wave 0/1 -> rows w*64..w*64+63 of block
    const int colw = lane & 15;
    const int quad = lane >> 4;

    // XCD-local linear tile id, then sqrt triangle decode (strips of 128).
    const int b = blockIdx.x;
    const int t = (b & 7) * 260 + (b >> 3);     // 2080 = 8 x 260
    int bi = (int)((sqrtf(8.0f * (float)t + 1.0f) - 1.0f) * 0.5f);
    while ((bi + 1) * (bi + 2) / 2 <= t) ++bi;
    while (bi * (bi + 1) / 2 > t) --bi;
    const int bj = t - bi * (bi + 1) / 2;

    const int rBase = bi * BMR;     // rows (A tile)
    const int cBase = bj * BNC;     // cols (B tile)

    // B staging (verbatim R12): tile = 128x64 elems = 1024 chunks of 16B;
    // 128 threads x 8 passes (rows srow + 16j). Slot (t&7) of row srow holds
    // global chunk (t&7) ^ (srow&7); srow&7 invariant under +16.
    const int srow = tid >> 3;                          // 0..15
    const int scol = (((tid & 7) ^ (srow & 7)) << 3);   // elem col 0..56
    const int e0   = tid * 8;                           // LDS elem offset/pass

    floatx4 acc[4][8];
    #pragma unroll
    for (int i = 0; i < 4; ++i)
        #pragma unroll
        for (int j = 0; j < 8; ++j)
            acc[i][j] = (floatx4)0.0f;

    // B fragment reads: row = nt*16 + colw; chunk (h*4+quad) at slot ^(colw&7).
    const int swz   = colw & 7;
    const int bRow0 = colw * BK;

    // A fragment base pointers: frag (mt,h) at aB[mt] + k0 + h*32.
    const unsigned short* aB[4];
    #pragma unroll
    for (int mt = 0; mt < 4; ++mt)
        aB[mt] = E + (size_t)(rBase + w * 64 + mt * 16 + colw) * DIM + quad * 8;

    const size_t gB0 = (size_t)(cBase + srow) * DIM + scol;
    const size_t rstep = (size_t)16 * DIM;

    // A register double-buffer: [parity][mt*2+h]
    bf16x8 aR[2][8];
    #pragma unroll
    for (int mt = 0; mt < 4; ++mt)
        #pragma unroll
        for (int h = 0; h < 2; ++h)
            aR[0][mt * 2 + h] = *(const bf16x8*)(aB[mt] + h * 32);

    #pragma unroll
    for (int it = 0; it < NITER; ++it) {
        const int cur = it & 1;           // compile-time under full unroll
        const int k0  = it * BK;
        __syncthreads();   // sync1: B LDS free
        #pragma unroll
        for (int j = 0; j < 8; ++j)
            async_load16(E + gB0 + j * rstep + k0, &sB[e0 + j * 1024]);
        __syncthreads();   // sync2: drains B(it) (A loads from last iter already landed)

        if (it + 1 < NITER) {
            // A prefetch for it+1: a full compute phase of slack before the
            // drain at sync2(it+1).
            #pragma unroll
            for (int mt = 0; mt < 4; ++mt)
                #pragma unroll
                for (int h = 0; h < 2; ++h)
                    aR[1 - cur][mt * 2 + h] =
                        *(const bf16x8*)(aB[mt] + k0 + BK + h * 32);
        }

        #pragma unroll
        for (int h = 0; h < 2; ++h) {
            const int cOff = (((h << 2) | quad) ^ swz) << 3;
            #pragma unroll
            for (int nt = 0; nt < 8; ++nt) {
                bf16x8 bF = *(const bf16x8*)&sB[bRow0 + nt * 16 * BK + cOff];
                #pragma unroll
                for (int mt = 0; mt < 4; ++mt)
                    acc[mt][nt] = __builtin_amdgcn_mfma_f32_16x16x32_bf16(
                        aR[cur][mt * 2 + h], bF, acc[mt][nt], 0, 0, 0);
            }
        }
    }

    // Epilogue. C/D layout (16x16x32): col = lane&15, row = quad*4 + reg.
    // Uniform rule (R11/R12-verified): element (grow, gcol) counts iff
    // grow > gcol; contributes to row grow AND col gcol.
    float labc[8];
    int   gcol[8];
    #pragma unroll
    for (int nt = 0; nt < 8; ++nt) {
        gcol[nt] = cBase + nt * 16 + colw;
        labc[nt] = (float)labels[gcol[nt]];
    }

    float colAll[8] = {0.f, 0.f, 0.f, 0.f, 0.f, 0.f, 0.f, 0.f};
    float colPos[8] = {0.f, 0.f, 0.f, 0.f, 0.f, 0.f, 0.f, 0.f};

    #pragma unroll
    for (int mt = 0; mt < 4; ++mt) {
        const int growBase = rBase + w * 64 + mt * 16 + quad * 4;
        #pragma unroll
        for (int r = 0; r < 4; ++r) {
            const int grow = growBase + r;
            const float labr = (float)labels[grow];
            float sAll = 0.f, sPos = 0.f;
            #pragma unroll
            for (int nt = 0; nt < 8; ++nt) {
                float ev = exp2f(acc[mt][nt][r]);   // PRESCALE folded into E
                ev = (grow > gcol[nt]) ? ev : 0.0f; // strictly-lower only
                sAll += ev;
                sPos += ev * labc[nt];
                colAll[nt] += ev;
                colPos[nt] += ev * labr;
            }
            // row-reduce across the 16 lanes (same quad) sharing this row
            #pragma unroll
            for (int off = 1; off < 16; off <<= 1) {
                sAll += __shfl_xor(sAll, off);
                sPos += __shfl_xor(sPos, off);
            }
            if (colw == 0 && sAll != 0.f) {
                atomicAdd(&all_sum[grow], sAll);
                atomicAdd(&pos_sum[grow], sPos);
            }
        }
    }

    // col-reduce: sum across quads (lanes differing in bits 4,5)
    #pragma unroll
    for (int nt = 0; nt < 8; ++nt) {
        float a = colAll[nt], p = colPos[nt];
        a += __shfl_xor(a, 16);  p += __shfl_xor(p, 16);
        a += __shfl_xor(a, 32);  p += __shfl_xor(p, 32);
        if (quad == 0 && a != 0.f) {
            atomicAdd(&all_sum[gcol[nt]], a);
            atomicAdd(&pos_sum[gcol[nt]], p);
        }
    }
}

// ---------------------------------------------------------------------------
// Kernel C: loss = mean over rows with lab==1 of -log(pos/(all+eps)); 0 if n_ref<2
// ---------------------------------------------------------------------------
__global__ __launch_bounds__(1024) void finalize_kernel(
    const float* __restrict__ all_sum,
    const float* __restrict__ pos_sum,
    const int*   __restrict__ labels,
    float*       __restrict__ out)
{
    __shared__ float sSum[1024];
    __shared__ float sCnt[1024];
    const int tid = threadIdx.x;
    float lsum = 0.f, lcnt = 0.f;
    for (int i = tid; i < NROWS; i += 1024) {
        if (labels[i] > 0) {
            float p = pos_sum[i];
            float a = all_sum[i] + EPS;
            lsum += -logf(p / a);
            lcnt += 1.0f;
        }
    }
    sSum[tid] = lsum;
    sCnt[tid] = lcnt;
    __syncthreads();
    for (int s = 512; s > 0; s >>= 1) {
        if (tid < s) { sSum[tid] += sSum[tid + s]; sCnt[tid] += sCnt[tid + s]; }
        __syncthreads();
    }
    if (tid == 0) {
        float n = sCnt[0];
        out[0] = (n < 2.0f) ? 0.0f : sSum[0] / fmaxf(n, 1.0f);
    }
}

// ---------------------------------------------------------------------------
extern "C" void kernel_launch(void* const* d_in, const int* in_sizes, int n_in,
                              void* d_out, int out_size, void* d_ws, size_t ws_size,
                              hipStream_t stream) {
    const float* emb    = (const float*)d_in[0];
    const int*   labels = (const int*)d_in[1];
    float*       out    = (float*)d_out;

    // workspace layout: [bf16 E: 16 MB][all_sum: 32 KB][pos_sum: 32 KB]
    unsigned short* Ebf = (unsigned short*)d_ws;
    const size_t embBytes = (size_t)NROWS * DIM * sizeof(unsigned short);
    float* all_sum = (float*)((char*)d_ws + embBytes);
    float* pos_sum = all_sum + NROWS;

    convert_kernel<<<(NROWS * DIM) / (4 * 256), 256, 0, stream>>>(emb, Ebf, all_sum);

    gemm_fused_kernel<<<NBLK, 128, 0, stream>>>(Ebf, labels, all_sum, pos_sum);

    finalize_kernel<<<1, 1024, 0, stream>>>(all_sum, pos_sum, labels, out);
}

// Round 15
// 198.119 us; speedup vs baseline: 2.7283x; 1.0061x over previous
//
#include <hip/hip_runtime.h>
#include <hip/hip_bf16.h>
#include <cstdint>
#include <cstddef>

// Problem constants (fixed shapes per reference)
#define NROWS 8192
#define DIM   1024
#define BMR 128           // block rows (2 waves x 64)
#define BNC 128           // block cols
#define BK  64            // K depth per iteration; 16 iterations
#define NITER (DIM / BK)
#define NBLK 2080         // 64*65/2 triangle tiles = 8 XCDs x 260
#define EPS 1e-8f
// E pre-scaled by sqrt(10*log2(e)) so MFMA accumulates 10*log2(e)*<a,b>;
// epilogue is a bare exp2f.
#define PRESCALE 3.798288f

typedef short  bf16x8  __attribute__((ext_vector_type(8)));
typedef float  floatx4 __attribute__((ext_vector_type(4)));

typedef __attribute__((address_space(1))) const void CGV;
typedef __attribute__((address_space(3))) void LV;

__device__ __forceinline__ void async_load16(const void* g, void* l) {
    __builtin_amdgcn_global_load_lds((CGV*)g, (LV*)l, 16, 0, 0);
}

__device__ __forceinline__ unsigned short f2bf_rne(float f) {
    union { float f; unsigned u; } c; c.f = f;
    unsigned u = c.u;
    unsigned r = (u + 0x7fffu + ((u >> 16) & 1u)) >> 16;
    return (unsigned short)r;
}

// ---------------------------------------------------------------------------
// Kernel A: fp32 -> bf16 (RNE) with PRESCALE folded in. First 64 blocks also
// zero the 16384-float accumulator region.
// ---------------------------------------------------------------------------
__global__ __launch_bounds__(256) void convert_kernel(
    const float* __restrict__ in, unsigned short* __restrict__ out,
    float* __restrict__ accum /* all_sum ++ pos_sum, 2*NROWS floats */)
{
    int i = (blockIdx.x * 256 + threadIdx.x) * 4;
    float4 v = *(const float4*)(in + i);
    ushort4 o;
    o.x = f2bf_rne(v.x * PRESCALE);
    o.y = f2bf_rne(v.y * PRESCALE);
    o.z = f2bf_rne(v.z * PRESCALE);
    o.w = f2bf_rne(v.w * PRESCALE);
    *(ushort4*)(out + i) = o;
    if (blockIdx.x < (2 * NROWS) / 256)
        accum[blockIdx.x * 256 + threadIdx.x] = 0.0f;
}

// ---------------------------------------------------------------------------
// Kernel B: symmetric-half fused GEMM — TRUE software pipeline with NO
// zero-slack drain (the common factor of every prior 110-137 us plateau):
//  * B tile: 2-stage LDS double-buffer; ONE raw barrier per K-iter:
//      s_waitcnt vmcnt(8) lgkmcnt(0); s_barrier
//    The 8 B-loads being waited on were issued a FULL compute phase earlier;
//    the 8 newest (next iter's A... see order below) stay in flight. Never
//    vmcnt(0) mid-loop. Mechanism correctness precedent: R5 (raw barriers +
//    manual vmcnt + global_load_lds + ds_read, bit-correct).
//  * A: direct global->VGPR register double-buffer (R14) — K-contiguous rows
//    need no LDS; compiler tracks those loads with per-register waits.
//  * Issue order pinned: B global_load_lds group, compiler barrier
//    (asm "":::"memory"), then A loads — so at the next barrier the oldest 8
//    outstanding VM ops are exactly B's, making vmcnt(8) => B landed.
//  * Fully unrolled: buffer parity compile-time (R5's VGPR-bloat avoided).
// LDS 2 x 16 KB = 32 KB -> 4 blocks/CU (4 barrier domains, R12-proven).
// B LDS swizzle verbatim R12 (0 conflicts). UNIFORM symmetry (R11/R12):
// keep strictly-lower (grow > gcol), feeds row grow AND col gcol.
// XCD-local tile order (R9).
// ---------------------------------------------------------------------------
__global__ __launch_bounds__(128, 2) void gemm_fused_kernel(
    const unsigned short* __restrict__ E,   // bf16 bits (prescaled), [NROWS][DIM]
    const int*            __restrict__ labels,
    float*                __restrict__ all_sum,
    float*                __restrict__ pos_sum)
{
    __shared__ __align__(16) unsigned short sB[2][BNC * BK];   // 2 x 16 KB

    const int tid  = threadIdx.x;
    const int lane = tid & 63;
    const int w    = tid >> 6;      // wave 0/1 -> rows w*64..w*64+63 of block
    const int colw = lane & 15;
    const int quad = lane >> 4;

    // XCD-local linear tile id, then sqrt triangle decode (strips of 128).
    const int b = blockIdx.x;
    const int t = (b & 7) * 260 + (b >> 3);     // 2080 = 8 x 260
    int bi = (int)((sqrtf(8.0f * (float)t + 1.0f) - 1.0f) * 0.5f);
    while ((bi + 1) * (bi + 2) / 2 <= t) ++bi;
    while (bi * (bi + 1) / 2 > t) --bi;
    const int bj = t - bi * (bi + 1) / 2;

    const int rBase = bi * BMR;     // rows (A tile)
    const int cBase = bj * BNC;     // cols (B tile)

    // B staging (verbatim R12): tile = 128x64 elems = 1024 chunks of 16B;
    // 128 threads x 8 passes (rows srow + 16j). Slot (t&7) of row srow holds
    // global chunk (t&7) ^ (srow&7); srow&7 invariant under +16.
    const int srow = tid >> 3;                          // 0..15
    const int scol = (((tid & 7) ^ (srow & 7)) << 3);   // elem col 0..56
    const int e0   = tid * 8;                           // LDS elem offset/pass

    floatx4 acc[4][8];
    #pragma unroll
    for (int i = 0; i < 4; ++i)
        #pragma unroll
        for (int j = 0; j < 8; ++j)
            acc[i][j] = (floatx4)0.0f;

    // B fragment reads: row = nt*16 + colw; chunk (h*4+quad) at slot ^(colw&7).
    const int swz   = colw & 7;
    const int bRow0 = colw * BK;

    // A fragment base pointers: frag (mt,h) at aB[mt] + k0 + h*32.
    const unsigned short* aB[4];
    #pragma unroll
    for (int mt = 0; mt < 4; ++mt)
        aB[mt] = E + (size_t)(rBase + w * 64 + mt * 16 + colw) * DIM + quad * 8;

    const size_t gB0 = (size_t)(cBase + srow) * DIM + scol;
    const size_t rstep = (size_t)16 * DIM;

    // ---- prologue: B(0) -> sB[0], then (order-pinned) A(0) -> aR[0] ----
    #pragma unroll
    for (int j = 0; j < 8; ++j)
        async_load16(E + gB0 + j * rstep, &sB[0][e0 + j * 1024]);
    asm volatile("" ::: "memory");   // pin VM issue order: B before A
    bf16x8 aR[2][8];
    #pragma unroll
    for (int mt = 0; mt < 4; ++mt)
        #pragma unroll
        for (int h = 0; h < 2; ++h)
            aR[0][mt * 2 + h] = *(const bf16x8*)(aB[mt] + h * 32);

    #pragma unroll
    for (int it = 0; it < NITER; ++it) {
        const int cur = it & 1;           // compile-time under full unroll
        // One barrier per iter. vmcnt(8): the oldest outstanding VM ops are
        // B(it)'s 8 global_load_lds (issued a full compute phase ago) ->
        // wait them; the 8 newest (A(it)) stay in flight. lgkmcnt(0) is free
        // (ds_reads already retired by MFMA-use waits).
        asm volatile("s_waitcnt vmcnt(8) lgkmcnt(0)\n\ts_barrier" ::: "memory");

        if (it + 1 < NITER) {
            const size_t kOff = (size_t)(it + 1) * BK;
            #pragma unroll
            for (int j = 0; j < 8; ++j)
                async_load16(E + gB0 + j * rstep + kOff,
                             &sB[1 - cur][e0 + j * 1024]);
            asm volatile("" ::: "memory");   // pin order: B before A
            #pragma unroll
            for (int mt = 0; mt < 4; ++mt)
                #pragma unroll
                for (int h = 0; h < 2; ++h)
                    aR[1 - cur][mt * 2 + h] =
                        *(const bf16x8*)(aB[mt] + kOff + h * 32);
        }

        #pragma unroll
        for (int h = 0; h < 2; ++h) {
            const int cOff = (((h << 2) | quad) ^ swz) << 3;
            #pragma unroll
            for (int nt = 0; nt < 8; ++nt) {
                bf16x8 bF = *(const bf16x8*)&sB[cur][bRow0 + nt * 16 * BK + cOff];
                #pragma unroll
                for (int mt = 0; mt < 4; ++mt)
                    acc[mt][nt] = __builtin_amdgcn_mfma_f32_16x16x32_bf16(
                        aR[cur][mt * 2 + h], bF, acc[mt][nt], 0, 0, 0);
            }
        }
    }

    // Epilogue. C/D layout (16x16x32): col = lane&15, row = quad*4 + reg.
    // Uniform rule (R11/R12-verified): element (grow, gcol) counts iff
    // grow > gcol; contributes to row grow AND col gcol.
    float labc[8];
    int   gcol[8];
    #pragma unroll
    for (int nt = 0; nt < 8; ++nt) {
        gcol[nt] = cBase + nt * 16 + colw;
        labc[nt] = (float)labels[gcol[nt]];
    }

    float colAll[8] = {0.f, 0.f, 0.f, 0.f, 0.f, 0.f, 0.f, 0.f};
    float colPos[8] = {0.f, 0.f, 0.f, 0.f, 0.f, 0.f, 0.f, 0.f};

    #pragma unroll
    for (int mt = 0; mt < 4; ++mt) {
        const int growBase = rBase + w * 64 + mt * 16 + quad * 4;
        #pragma unroll
        for (int r = 0; r < 4; ++r) {
            const int grow = growBase + r;
            const float labr = (float)labels[grow];
            float sAll = 0.f, sPos = 0.f;
            #pragma unroll
            for (int nt = 0; nt < 8; ++nt) {
                float ev = exp2f(acc[mt][nt][r]);   // PRESCALE folded into E
                ev = (grow > gcol[nt]) ? ev : 0.0f; // strictly-lower only
                sAll += ev;
                sPos += ev * labc[nt];
                colAll[nt] += ev;
                colPos[nt] += ev * labr;
            }
            // row-reduce across the 16 lanes (same quad) sharing this row
            #pragma unroll
            for (int off = 1; off < 16; off <<= 1) {
                sAll += __shfl_xor(sAll, off);
                sPos += __shfl_xor(sPos, off);
            }
            if (colw == 0 && sAll != 0.f) {
                atomicAdd(&all_sum[grow], sAll);
                atomicAdd(&pos_sum[grow], sPos);
            }
        }
    }

    // col-reduce: sum across quads (lanes differing in bits 4,5)
    #pragma unroll
    for (int nt = 0; nt < 8; ++nt) {
        float a = colAll[nt], p = colPos[nt];
        a += __shfl_xor(a, 16);  p += __shfl_xor(p, 16);
        a += __shfl_xor(a, 32);  p += __shfl_xor(p, 32);
        if (quad == 0 && a != 0.f) {
            atomicAdd(&all_sum[gcol[nt]], a);
            atomicAdd(&pos_sum[gcol[nt]], p);
        }
    }
}

// ---------------------------------------------------------------------------
// Kernel C: loss = mean over rows with lab==1 of -log(pos/(all+eps)); 0 if n_ref<2
// ---------------------------------------------------------------------------
__global__ __launch_bounds__(1024) void finalize_kernel(
    const float* __restrict__ all_sum,
    const float* __restrict__ pos_sum,
    const int*   __restrict__ labels,
    float*       __restrict__ out)
{
    __shared__ float sSum[1024];
    __shared__ float sCnt[1024];
    const int tid = threadIdx.x;
    float lsum = 0.f, lcnt = 0.f;
    for (int i = tid; i < NROWS; i += 1024) {
        if (labels[i] > 0) {
            float p = pos_sum[i];
            float a = all_sum[i] + EPS;
            lsum += -logf(p / a);
            lcnt += 1.0f;
        }
    }
    sSum[tid] = lsum;
    sCnt[tid] = lcnt;
    __syncthreads();
    for (int s = 512; s > 0; s >>= 1) {
        if (tid < s) { sSum[tid] += sSum[tid + s]; sCnt[tid] += sCnt[tid + s]; }
        __syncthreads();
    }
    if (tid == 0) {
        float n = sCnt[0];
        out[0] = (n < 2.0f) ? 0.0f : sSum[0] / fmaxf(n, 1.0f);
    }
}

// ---------------------------------------------------------------------------
extern "C" void kernel_launch(void* const* d_in, const int* in_sizes, int n_in,
                              void* d_out, int out_size, void* d_ws, size_t ws_size,
                              hipStream_t stream) {
    const float* emb    = (const float*)d_in[0];
    const int*   labels = (const int*)d_in[1];
    float*       out    = (float*)d_out;

    // workspace layout: [bf16 E: 16 MB][all_sum: 32 KB][pos_sum: 32 KB]
    unsigned short* Ebf = (unsigned short*)d_ws;
    const size_t embBytes = (size_t)NROWS * DIM * sizeof(unsigned short);
    float* all_sum = (float*)((char*)d_ws + embBytes);
    float* pos_sum = all_sum + NROWS;

    convert_kernel<<<(NROWS * DIM) / (4 * 256), 256, 0, stream>>>(emb, Ebf, all_sum);

    gemm_fused_kernel<<<NBLK, 128, 0, stream>>>(Ebf, labels, all_sum, pos_sum);

    finalize_kernel<<<1, 1024, 0, stream>>>(all_sum, pos_sum, labels, out);
}